// Round 17
// baseline (401.001 us; speedup 1.0000x reference)
//
#include <hip/hip_runtime.h>
#include <cstdint>
#include <cstddef>

// GRU (reset_after) + dense(1)+sigmoid, masked by per-batch length t.
// R17 = R16 with `__exp2f` -> `exp2f` (glibc macro collision fix).
//  1. SOFTWARE-PIPELINED DS round-trip: step s+1's h-reads (and x-reads)
//     are issued right after step s's h-write, so the ~200cy DS latency
//     overlaps the loop tail + next step's register-resident W block
//     instead of being exposed at the step head.
//  2. log2(e) folded into f16 weights/biases (plain C++ fold) + exp2f
//     (v_exp_f32, compiler-handled hazards) -- removes the hidden v_mul
//     inside every __expf from 3 serial chains.
//  3. U-dots ordered r/z first (alternating), exp2 early, c-dots (2 accs)
//     last so both sigmoid chains cook under the c issue stream.
// Structure unchanged: ONE WAVE per sequence (512 x 64), ZERO barriers,
// lane j owns gate cols {j,64+j,128+j} full-K via v_dot2_f32_f16,
// h state f16 in LDS (same-wave write->read).

typedef float  v2f __attribute__((ext_vector_type(2)));
typedef float  v4f __attribute__((ext_vector_type(4)));
typedef _Float16 h2 __attribute__((ext_vector_type(2)));
typedef _Float16 h8 __attribute__((ext_vector_type(8)));

__device__ __forceinline__ float frcp(float x) { return __builtin_amdgcn_rcpf(x); }

#if defined(__has_builtin)
#if __has_builtin(__builtin_amdgcn_fdot2)
#define HAVE_FDOT2 1
#endif
#endif

__device__ __forceinline__ float fdot2(h2 a, h2 b, float acc) {
#ifdef HAVE_FDOT2
    return __builtin_amdgcn_fdot2(a, b, acc, false);
#else
    return fmaf((float)a.x, (float)b.x, fmaf((float)a.y, (float)b.y, acc));
#endif
}

#define PAIR(v8, m) __builtin_shufflevector((v8), (v8), 2*(m), 2*(m)+1)

// W-part: r/z/c trios (regs-only, fills the pipelined-read window)
#define WTRIO(off, v, m)                                     \
    rw = fdot2(Wr[(off)+(m)], PAIR((v),(m)), rw);            \
    zw = fdot2(Wz[(off)+(m)], PAIR((v),(m)), zw);            \
    cw = fdot2(Wc[(off)+(m)], PAIR((v),(m)), cw);
#define WTRIO4(off, v) WTRIO(off, v, 0) WTRIO(off, v, 1) WTRIO(off, v, 2) WTRIO(off, v, 3)

// U-part phase 1: r,z alternating (dep distance 2 instrs ~= latency)
#define URZ(off, v, m)                                       \
    ru = fdot2(Ur[(off)+(m)], PAIR((v),(m)), ru);            \
    zu = fdot2(Uz[(off)+(m)], PAIR((v),(m)), zu);
#define URZ4(off, v) URZ(off, v, 0) URZ(off, v, 1) URZ(off, v, 2) URZ(off, v, 3)

// U-part phase 2: c with two alternating accumulators
#define UC4(off, v)                                          \
    cu0 = fdot2(Uc[(off)+0], PAIR((v),0), cu0);              \
    cu1 = fdot2(Uc[(off)+1], PAIR((v),1), cu1);              \
    cu0 = fdot2(Uc[(off)+2], PAIR((v),2), cu0);              \
    cu1 = fdot2(Uc[(off)+3], PAIR((v),3), cu1);

__global__ __launch_bounds__(64, 1) void gru1_kernel(
    const float* __restrict__ xg,      // (512,1024,24)
    const int*   __restrict__ tg,      // (512,)
    const float* __restrict__ Wg,      // (24,192)
    const float* __restrict__ Ug,      // (64,192)
    const float* __restrict__ bg,      // (2,192)
    const float* __restrict__ Wdg,     // (64,1)
    const float* __restrict__ bdg,     // (1,)
    float*       __restrict__ outg)    // (512,1024)
{
    const int b = blockIdx.x;
    const int j = threadIdx.x;          // lane 0..63

    __shared__ __align__(16) _Float16 h16[64];          // f16 state, 128 B
    __shared__ __align__(16) _Float16 xbuf[64 * 24];    // chunk of x, f16
    __shared__ __align__(16) float    p_lds[64 * 66];   // [step][lane], pad 66
    __shared__ float o_last;

    const int   t    = tg[b];
    float*      outb = outg + (size_t)b * 1024;
    const float bdv  = bdg[0];

    if (t <= 0) {
        const float fill = frcp(1.f + __expf(-bdv));
        for (int i = j; i < 1024; i += 64) outb[i] = fill;
        return;
    }

    const float L2E = 1.4426950408889634f;  // log2(e)

    // ---- weight preload: f16 pairs along K ----
    // z,r scaled by -log2e (sigmoid(v) = rcp(1+exp2(-log2e*v)))
    // c   scaled by 2*log2e (tanh(u) = 1 - 2*rcp(1+exp2(2*log2e*u)))
    h2 Uz[32], Ur[32], Uc[32];
    #pragma unroll
    for (int k = 0; k < 32; ++k) {
        const float* r0 = Ug + (2 * k)     * 192;
        const float* r1 = Ug + (2 * k + 1) * 192;
        Uz[k] = (h2){ (_Float16)(-L2E * r0[j]),            (_Float16)(-L2E * r1[j]) };
        Ur[k] = (h2){ (_Float16)(-L2E * r0[64 + j]),       (_Float16)(-L2E * r1[64 + j]) };
        Uc[k] = (h2){ (_Float16)(2.f * L2E * r0[128 + j]), (_Float16)(2.f * L2E * r1[128 + j]) };
    }
    h2 Wz[12], Wr[12], Wc[12];
    #pragma unroll
    for (int d = 0; d < 12; ++d) {
        const float* r0 = Wg + (2 * d)     * 192;
        const float* r1 = Wg + (2 * d + 1) * 192;
        Wz[d] = (h2){ (_Float16)(-L2E * r0[j]),            (_Float16)(-L2E * r1[j]) };
        Wr[d] = (h2){ (_Float16)(-L2E * r0[64 + j]),       (_Float16)(-L2E * r1[64 + j]) };
        Wc[d] = (h2){ (_Float16)(2.f * L2E * r0[128 + j]), (_Float16)(2.f * L2E * r1[128 + j]) };
    }
    const float bzn  = -L2E * (bg[j]      + bg[192 + j]);
    const float brn  = -L2E * (bg[64 + j] + bg[256 + j]);
    const float b0c2 = 2.f * L2E * bg[128 + j];
    const float b1c2 = 2.f * L2E * bg[320 + j];
    const float wdj  = Wdg[j];

    const float* xb = xg + (size_t)b * 24576;   // 1024*24

    // ---- stage chunk 0: lane j handles x row j (24 f32 -> 24 f16) ----
    {
        const v4f* src = (const v4f*)(xb + j * 24);
        v4f g0 = src[0], g1 = src[1], g2 = src[2], g3 = src[3], g4 = src[4], g5 = src[5];
        h8 o0, o1, o2;
        #pragma unroll
        for (int i = 0; i < 4; ++i) {
            o0[i]     = (_Float16)g0[i];  o0[4 + i] = (_Float16)g1[i];
            o1[i]     = (_Float16)g2[i];  o1[4 + i] = (_Float16)g3[i];
            o2[i]     = (_Float16)g4[i];  o2[4 + i] = (_Float16)g5[i];
        }
        h8* dst = (h8*)(xbuf + j * 24);
        dst[0] = o0; dst[1] = o1; dst[2] = o2;
    }
    h16[j] = (_Float16)0.f;

    // prefetch chunk 1 (f32, converted at commit)
    v4f pf[6];
    if (t > 64) {
        const v4f* ns = (const v4f*)(xb + 1536 + j * 24);
        #pragma unroll
        for (int i = 0; i < 6; ++i) pf[i] = ns[i];
    }

    float hold = 0.f;   // lane j's own h_j (f32, full precision)

    // ---- pipeline prologue: hv and x row 0 in registers ----
    h8 hv[8];
    {
        const h8* hp = (const h8*)h16;
        #pragma unroll
        for (int i = 0; i < 8; ++i) hv[i] = hp[i];
    }
    h8 xa, xcv, xe;
    {
        const h8* xp = (const h8*)xbuf;
        xa = xp[0]; xcv = xp[1]; xe = xp[2];
    }

    for (int base = 0; base < t; base += 64) {
        const int cnt = (t - base < 64) ? (t - base) : 64;

        if (base > 0) {
            // previous chunk done. Reduce its outputs (before p_lds reuse),
            // commit prefetched x, prefetch next. Same-wave ordering only.
            {
                const v2f* pr = (const v2f*)(p_lds + j * 66);
                v2f s2 = (v2f){0.f, 0.f};
                #pragma unroll
                for (int i = 0; i < 32; ++i) s2 += pr[i];
                outb[base - 64 + j] = frcp(1.f + __expf(-(s2.x + s2.y + bdv)));
            }
            {
                h8 o0, o1, o2;
                #pragma unroll
                for (int i = 0; i < 4; ++i) {
                    o0[i]     = (_Float16)pf[0][i];  o0[4 + i] = (_Float16)pf[1][i];
                    o1[i]     = (_Float16)pf[2][i];  o1[4 + i] = (_Float16)pf[3][i];
                    o2[i]     = (_Float16)pf[4][i];  o2[4 + i] = (_Float16)pf[5][i];
                }
                h8* dst = (h8*)(xbuf + j * 24);
                dst[0] = o0; dst[1] = o1; dst[2] = o2;
            }
            if (base + 64 < t) {
                const v4f* ns = (const v4f*)(xb + (size_t)(base + 64) * 24 + j * 24);
                #pragma unroll
                for (int i = 0; i < 6; ++i) pf[i] = ns[i];
            }
            // re-read x row 0 of the freshly committed chunk (pipelined
            // regs hold stale-chunk data); hv carries over (h16 untouched)
            const h8* xp = (const h8*)xbuf;
            xa = xp[0]; xcv = xp[1]; xe = xp[2];
        }

        for (int c = 0; c < cnt; ++c) {
            // ---- W block on registers (fills the pipelined-read window) ----
            float rw = brn, zw = bzn, cw = b0c2;
            WTRIO4(0, xa) WTRIO4(4, xcv) WTRIO4(8, xe)

            // ---- U phase 1: r,z alternating ----
            float ru = 0.f, zu = 0.f;
            URZ4( 0, hv[0]) URZ4( 4, hv[1]) URZ4( 8, hv[2]) URZ4(12, hv[3])
            URZ4(16, hv[4]) URZ4(20, hv[5]) URZ4(24, hv[6]) URZ4(28, hv[7])
            const float er = exp2f(rw + ru);   // cooks under c dots
            const float ez = exp2f(zw + zu);   // cooks under c dots

            // ---- U phase 2: c dots, two alternating accumulators ----
            float cu0 = b1c2, cu1 = 0.f;
            UC4( 0, hv[0]) UC4( 4, hv[1]) UC4( 8, hv[2]) UC4(12, hv[3])
            UC4(16, hv[4]) UC4(20, hv[5]) UC4(24, hv[6]) UC4(28, hv[7])

            const float r  = frcp(1.f + er);
            const float z  = frcp(1.f + ez);
            const float y2 = fmaf(r, cu0 + cu1, cw);            // 2L2E*(xc+r*hc)
            const float cg = 1.f - 2.f * frcp(1.f + exp2f(y2));
            const float hn = fmaf(z, hold - cg, cg);            // z*h + (1-z)*c
            hold = hn;

            // ---- write h FIRST, then pipeline next step's DS reads ----
            h16[j] = (_Float16)hn;
            h8 nhv[8];
            {
                const h8* hp = (const h8*)h16;
                #pragma unroll
                for (int i = 0; i < 8; ++i) nhv[i] = hp[i];
            }
            const h8* xp = (const h8*)(xbuf + ((c + 1) & 63) * 24);
            const h8 nxa = xp[0], nxcv = xp[1], nxe = xp[2];

            p_lds[c * 66 + j] = hn * wdj;   // output partial (queue tail)

            #pragma unroll
            for (int i = 0; i < 8; ++i) hv[i] = nhv[i];
            xa = nxa; xcv = nxcv; xe = nxe;
        }
    }

    // ---- final (possibly partial) chunk reduce ----
    const int lastbase = ((t - 1) >> 6) << 6;
    const int lastcnt  = t - lastbase;
    if (j < lastcnt) {
        const v2f* pr = (const v2f*)(p_lds + j * 66);
        v2f s2 = (v2f){0.f, 0.f};
        #pragma unroll
        for (int i = 0; i < 32; ++i) s2 += pr[i];
        const float o = frcp(1.f + __expf(-(s2.x + s2.y + bdv)));
        outb[lastbase + j] = o;
        if (j == lastcnt - 1) o_last = o;
    }
    // ---- constant tail fill (same-wave visibility; R3-proven pattern) ----
    const float fill = o_last;
    for (int i = t + j; i < 1024; i += 64) outb[i] = fill;
}

extern "C" void kernel_launch(void* const* d_in, const int* in_sizes, int n_in,
                              void* d_out, int out_size, void* d_ws, size_t ws_size,
                              hipStream_t stream) {
    (void)in_sizes; (void)n_in; (void)d_ws; (void)ws_size; (void)out_size;
    const float* x  = (const float*)d_in[0];
    const int*   t  = (const int*)d_in[1];
    const float* W  = (const float*)d_in[2];
    const float* U  = (const float*)d_in[3];
    const float* bb = (const float*)d_in[4];
    const float* Wd = (const float*)d_in[5];
    const float* bd = (const float*)d_in[6];
    float* out = (float*)d_out;

    hipLaunchKernelGGL(gru1_kernel, dim3(512), dim3(64), 0, stream,
                       x, t, W, U, bb, Wd, bd, out);
}

// Round 18
// 400.180 us; speedup vs baseline: 1.0021x; 1.0021x over previous
//
#include <hip/hip_runtime.h>
#include <cstdint>
#include <cstddef>

// GRU (reset_after) + dense(1)+sigmoid, masked by per-batch length t.
// R18 = R12 with ONE variable changed: dot emission is a 6-way ROUND-ROBIN
// at SINGLE-DOT granularity (accumulators r/z/c x 2 each; reuse distance
// 6 instrs ~= 12cy). Hypothesis: v_dot2_f32_f16 dependent latency ~8cy >
// R15's 3-way spacing (6cy), explaining the persistent ~200-300cy stall
// (R13 never tested this: its DOT4 kept 4 dependent dots contiguous).
// Math identical to R12 (same folds, __expf) -- pure reassociation.
// Structure unchanged: ONE WAVE per sequence (512 x 64), ZERO barriers,
// lane j owns gate cols {j,64+j,128+j} full-K via v_dot2_f32_f16,
// h state f16 in LDS (same-wave write->read), z/r weights pre-negated,
// c weights pre-doubled.

typedef float  v2f __attribute__((ext_vector_type(2)));
typedef float  v4f __attribute__((ext_vector_type(4)));
typedef _Float16 h2 __attribute__((ext_vector_type(2)));
typedef _Float16 h8 __attribute__((ext_vector_type(8)));

__device__ __forceinline__ float frcp(float x) { return __builtin_amdgcn_rcpf(x); }

#if defined(__has_builtin)
#if __has_builtin(__builtin_amdgcn_fdot2)
#define HAVE_FDOT2 1
#endif
#endif

__device__ __forceinline__ float fdot2(h2 a, h2 b, float acc) {
#ifdef HAVE_FDOT2
    return __builtin_amdgcn_fdot2(a, b, acc, false);
#else
    return fmaf((float)a.x, (float)b.x, fmaf((float)a.y, (float)b.y, acc));
#endif
}

#define PAIR(v8, m) __builtin_shufflevector((v8), (v8), 2*(m), 2*(m)+1)

// U-part: 6-acc single-dot round-robin over one h8 vector (4 pairs)
#define USIX(off, v)                                          \
    ru0 = fdot2(Ur[(off)+0], PAIR((v),0), ru0);               \
    zu0 = fdot2(Uz[(off)+0], PAIR((v),0), zu0);               \
    cu0 = fdot2(Uc[(off)+0], PAIR((v),0), cu0);               \
    ru1 = fdot2(Ur[(off)+1], PAIR((v),1), ru1);               \
    zu1 = fdot2(Uz[(off)+1], PAIR((v),1), zu1);               \
    cu1 = fdot2(Uc[(off)+1], PAIR((v),1), cu1);               \
    ru0 = fdot2(Ur[(off)+2], PAIR((v),2), ru0);               \
    zu0 = fdot2(Uz[(off)+2], PAIR((v),2), zu0);               \
    cu0 = fdot2(Uc[(off)+2], PAIR((v),2), cu0);               \
    ru1 = fdot2(Ur[(off)+3], PAIR((v),3), ru1);               \
    zu1 = fdot2(Uz[(off)+3], PAIR((v),3), zu1);               \
    cu1 = fdot2(Uc[(off)+3], PAIR((v),3), cu1);

// W-part: same 6-acc round-robin
#define WSIX(off, v)                                          \
    rw0 = fdot2(Wr[(off)+0], PAIR((v),0), rw0);               \
    zw0 = fdot2(Wz[(off)+0], PAIR((v),0), zw0);               \
    cw0 = fdot2(Wc[(off)+0], PAIR((v),0), cw0);               \
    rw1 = fdot2(Wr[(off)+1], PAIR((v),1), rw1);               \
    zw1 = fdot2(Wz[(off)+1], PAIR((v),1), zw1);               \
    cw1 = fdot2(Wc[(off)+1], PAIR((v),1), cw1);               \
    rw0 = fdot2(Wr[(off)+2], PAIR((v),2), rw0);               \
    zw0 = fdot2(Wz[(off)+2], PAIR((v),2), zw0);               \
    cw0 = fdot2(Wc[(off)+2], PAIR((v),2), cw0);               \
    rw1 = fdot2(Wr[(off)+3], PAIR((v),3), rw1);               \
    zw1 = fdot2(Wz[(off)+3], PAIR((v),3), zw1);               \
    cw1 = fdot2(Wc[(off)+3], PAIR((v),3), cw1);

__global__ __launch_bounds__(64, 1) void gru1_kernel(
    const float* __restrict__ xg,      // (512,1024,24)
    const int*   __restrict__ tg,      // (512,)
    const float* __restrict__ Wg,      // (24,192)
    const float* __restrict__ Ug,      // (64,192)
    const float* __restrict__ bg,      // (2,192)
    const float* __restrict__ Wdg,     // (64,1)
    const float* __restrict__ bdg,     // (1,)
    float*       __restrict__ outg)    // (512,1024)
{
    const int b = blockIdx.x;
    const int j = threadIdx.x;          // lane 0..63

    __shared__ __align__(16) _Float16 h16[64];          // f16 state, 128 B
    __shared__ __align__(16) _Float16 xbuf[64 * 24];    // chunk of x, f16
    __shared__ __align__(16) float    p_lds[64 * 66];   // [step][lane], pad 66
    __shared__ float o_last;

    const int   t    = tg[b];
    float*      outb = outg + (size_t)b * 1024;
    const float bdv  = bdg[0];

    if (t <= 0) {
        const float fill = frcp(1.f + __expf(-bdv));
        for (int i = j; i < 1024; i += 64) outb[i] = fill;
        return;
    }

    // ---- weight preload: f16 pairs along K; z/r negated, c doubled ----
    h2 Uz[32], Ur[32], Uc[32];
    #pragma unroll
    for (int k = 0; k < 32; ++k) {
        const float* r0 = Ug + (2 * k)     * 192;
        const float* r1 = Ug + (2 * k + 1) * 192;
        Uz[k] = (h2){ (_Float16)(-r0[j]),            (_Float16)(-r1[j]) };
        Ur[k] = (h2){ (_Float16)(-r0[64 + j]),       (_Float16)(-r1[64 + j]) };
        Uc[k] = (h2){ (_Float16)(2.f * r0[128 + j]), (_Float16)(2.f * r1[128 + j]) };
    }
    h2 Wz[12], Wr[12], Wc[12];
    #pragma unroll
    for (int d = 0; d < 12; ++d) {
        const float* r0 = Wg + (2 * d)     * 192;
        const float* r1 = Wg + (2 * d + 1) * 192;
        Wz[d] = (h2){ (_Float16)(-r0[j]),            (_Float16)(-r1[j]) };
        Wr[d] = (h2){ (_Float16)(-r0[64 + j]),       (_Float16)(-r1[64 + j]) };
        Wc[d] = (h2){ (_Float16)(2.f * r0[128 + j]), (_Float16)(2.f * r1[128 + j]) };
    }
    const float bzn  = -(bg[j]      + bg[192 + j]);     // z: negated
    const float brn  = -(bg[64 + j] + bg[256 + j]);     // r: negated
    const float b0c2 = 2.f * bg[128 + j];               // c: doubled
    const float b1c2 = 2.f * bg[320 + j];
    const float wdj  = Wdg[j];

    const float* xb = xg + (size_t)b * 24576;   // 1024*24

    // ---- stage chunk 0: lane j handles x row j (24 f32 -> 24 f16) ----
    {
        const v4f* src = (const v4f*)(xb + j * 24);
        v4f g0 = src[0], g1 = src[1], g2 = src[2], g3 = src[3], g4 = src[4], g5 = src[5];
        h8 o0, o1, o2;
        #pragma unroll
        for (int i = 0; i < 4; ++i) {
            o0[i]     = (_Float16)g0[i];  o0[4 + i] = (_Float16)g1[i];
            o1[i]     = (_Float16)g2[i];  o1[4 + i] = (_Float16)g3[i];
            o2[i]     = (_Float16)g4[i];  o2[4 + i] = (_Float16)g5[i];
        }
        h8* dst = (h8*)(xbuf + j * 24);
        dst[0] = o0; dst[1] = o1; dst[2] = o2;
    }
    h16[j] = (_Float16)0.f;

    // prefetch chunk 1 (f32, converted at commit)
    v4f pf[6];
    if (t > 64) {
        const v4f* ns = (const v4f*)(xb + 1536 + j * 24);
        #pragma unroll
        for (int i = 0; i < 6; ++i) pf[i] = ns[i];
    }

    float hold = 0.f;   // lane j's own h_j (f32, full precision)

    for (int base = 0; base < t; base += 64) {
        const int cnt = (t - base < 64) ? (t - base) : 64;

        if (base > 0) {
            // previous chunk done. Reduce its outputs (before p_lds reuse),
            // commit prefetched x, prefetch next. Same-wave ordering only.
            {
                const v2f* pr = (const v2f*)(p_lds + j * 66);
                v2f s2 = (v2f){0.f, 0.f};
                #pragma unroll
                for (int i = 0; i < 32; ++i) s2 += pr[i];
                outb[base - 64 + j] = frcp(1.f + __expf(-(s2.x + s2.y + bdv)));
            }
            {
                h8 o0, o1, o2;
                #pragma unroll
                for (int i = 0; i < 4; ++i) {
                    o0[i]     = (_Float16)pf[0][i];  o0[4 + i] = (_Float16)pf[1][i];
                    o1[i]     = (_Float16)pf[2][i];  o1[4 + i] = (_Float16)pf[3][i];
                    o2[i]     = (_Float16)pf[4][i];  o2[4 + i] = (_Float16)pf[5][i];
                }
                h8* dst = (h8*)(xbuf + j * 24);
                dst[0] = o0; dst[1] = o1; dst[2] = o2;
            }
            if (base + 64 < t) {
                const v4f* ns = (const v4f*)(xb + (size_t)(base + 64) * 24 + j * 24);
                #pragma unroll
                for (int i = 0; i < 6; ++i) pf[i] = ns[i];
            }
        }

        for (int c = 0; c < cnt; ++c) {
            // ---- issue x reads first (needed by the W block), then h ----
            const h8* xp = (const h8*)(xbuf + c * 24);
            h8 xa = xp[0], xcv = xp[1], xe = xp[2];
            const h8* hp = (const h8*)h16;
            h8 hv[8];
            #pragma unroll
            for (int i = 0; i < 8; ++i) hv[i] = hp[i];

            // ---- W block: 36 dots, 6-acc round-robin ----
            float rw0 = brn, zw0 = bzn, cw0 = b0c2;
            float rw1 = 0.f, zw1 = 0.f, cw1 = 0.f;
            WSIX(0, xa) WSIX(4, xcv) WSIX(8, xe)

            // ---- U block: 96 dots, 6-acc round-robin (reuse distance
            //      6 instrs ~12cy > dot2 dep latency -> stall-free) ----
            float ru0 = 0.f, zu0 = 0.f, cu0 = b1c2;
            float ru1 = 0.f, zu1 = 0.f, cu1 = 0.f;
            USIX( 0, hv[0]) USIX( 4, hv[1]) USIX( 8, hv[2]) USIX(12, hv[3])
            USIX(16, hv[4]) USIX(20, hv[5]) USIX(24, hv[6]) USIX(28, hv[7])

            // ---- merge + gates ----
            const float ran = (ru0 + ru1) + (rw0 + rw1);
            const float zan = (zu0 + zu1) + (zw0 + zw1);
            const float er  = __expf(ran);
            const float ez  = __expf(zan);
            const float r   = frcp(1.f + er);
            const float z   = frcp(1.f + ez);
            const float y   = fmaf(r, cu0 + cu1, cw0 + cw1);   // 2*(xc + r*hc)
            const float cg  = 1.f - 2.f * frcp(1.f + __expf(y));
            const float hn  = fmaf(z, hold - cg, cg);          // z*h + (1-z)*c
            hold = hn;

            h16[j] = (_Float16)hn;          // next step's state (ds_write_b16)
            p_lds[c * 66 + j] = hn * wdj;   // output partial
        }
    }

    // ---- final (possibly partial) chunk reduce ----
    const int lastbase = ((t - 1) >> 6) << 6;
    const int lastcnt  = t - lastbase;
    if (j < lastcnt) {
        const v2f* pr = (const v2f*)(p_lds + j * 66);
        v2f s2 = (v2f){0.f, 0.f};
        #pragma unroll
        for (int i = 0; i < 32; ++i) s2 += pr[i];
        const float o = frcp(1.f + __expf(-(s2.x + s2.y + bdv)));
        outb[lastbase + j] = o;
        if (j == lastcnt - 1) o_last = o;
    }
    // ---- constant tail fill (same-wave visibility; R3-proven pattern) ----
    const float fill = o_last;
    for (int i = t + j; i < 1024; i += 64) outb[i] = fill;
}

extern "C" void kernel_launch(void* const* d_in, const int* in_sizes, int n_in,
                              void* d_out, int out_size, void* d_ws, size_t ws_size,
                              hipStream_t stream) {
    (void)in_sizes; (void)n_in; (void)d_ws; (void)ws_size; (void)out_size;
    const float* x  = (const float*)d_in[0];
    const int*   t  = (const int*)d_in[1];
    const float* W  = (const float*)d_in[2];
    const float* U  = (const float*)d_in[3];
    const float* bb = (const float*)d_in[4];
    const float* Wd = (const float*)d_in[5];
    const float* bd = (const float*)d_in[6];
    float* out = (float*)d_out;

    hipLaunchKernelGGL(gru1_kernel, dim3(512), dim3(64), 0, stream,
                       x, t, W, U, bb, Wd, bd, out);
}

// Round 19
// 363.971 us; speedup vs baseline: 1.1017x; 1.0995x over previous
//
#include <hip/hip_runtime.h>
#include <cstdint>
#include <cstddef>

// GRU (reset_after) + dense(1)+sigmoid, masked by per-batch length t.
// R19 = R12 body (proven 377us floor) with TWO register-pressure/latency
// changes attacking the same binder:
//  1. 2x-UNROLLED PING-PONG pipeline (R17 minus its fatal 32-reg copy
//     loop): step c computes on register set A and issues set B's h/x
//     LDS reads immediately after its h-write; step c+1 computes on B
//     and refills A. The ~200cy DS round-trip overlaps the gate tail +
//     the next step's register-resident W block.
//  2. x-prefetch registers DROPPED (global read directly at the 16 chunk
//     boundaries, ~10cy/step amortized) so the live set (~132 weight +
//     2x32 hv + 2x12 x + misc ~= 230) fits under 256 VGPRs -- R12's
//     VGPR_Count=152 < ~200 live proves the compiler was live-range
//     splitting (in-loop LDS/global re-reads), an unmodeled stall.
// Structure unchanged: ONE WAVE per sequence (512 x 64), ZERO barriers,
// lane j owns gate cols {j,64+j,128+j} full-K via v_dot2_f32_f16,
// h state f16 in LDS (same-wave write->read), z/r weights pre-negated,
// c weights pre-doubled.

typedef float  v2f __attribute__((ext_vector_type(2)));
typedef float  v4f __attribute__((ext_vector_type(4)));
typedef _Float16 h2 __attribute__((ext_vector_type(2)));
typedef _Float16 h8 __attribute__((ext_vector_type(8)));

__device__ __forceinline__ float frcp(float x) { return __builtin_amdgcn_rcpf(x); }

#if defined(__has_builtin)
#if __has_builtin(__builtin_amdgcn_fdot2)
#define HAVE_FDOT2 1
#endif
#endif

__device__ __forceinline__ float fdot2(h2 a, h2 b, float acc) {
#ifdef HAVE_FDOT2
    return __builtin_amdgcn_fdot2(a, b, acc, false);
#else
    return fmaf((float)a.x, (float)b.x, fmaf((float)a.y, (float)b.y, acc));
#endif
}

#define PAIR(v8, m) __builtin_shufflevector((v8), (v8), 2*(m), 2*(m)+1)

// 4 dot2s against one h8 vector, all pair indices literal
#define DOT4(acc, Warr, off, v)                              \
    acc = fdot2((Warr)[(off) + 0], PAIR((v), 0), acc);       \
    acc = fdot2((Warr)[(off) + 1], PAIR((v), 1), acc);       \
    acc = fdot2((Warr)[(off) + 2], PAIR((v), 2), acc);       \
    acc = fdot2((Warr)[(off) + 3], PAIR((v), 3), acc);

// One full GRU step on register set (HV, X0..X2); after the h-write it
// issues the NEXT step's LDS reads into (NHV, NX0..NX2) -- ping-pong, no
// copies. p-write goes after the reads (off the critical DS queue head).
#define GRU_STEP(C, HV, X0, X1, X2, NHV, NX0, NX1, NX2)                     \
  { float ran = brn;                                                        \
    DOT4(ran, Wr, 0, X0) DOT4(ran, Wr, 4, X1) DOT4(ran, Wr, 8, X2)          \
    float zan = bzn;                                                        \
    DOT4(zan, Wz, 0, X0) DOT4(zan, Wz, 4, X1) DOT4(zan, Wz, 8, X2)          \
    float xca = b0c2;                                                       \
    DOT4(xca, Wc, 0, X0) DOT4(xca, Wc, 4, X1) DOT4(xca, Wc, 8, X2)          \
    _Pragma("unroll")                                                       \
    for (int i = 0; i < 8; ++i) { DOT4(ran, Ur, 4 * i, HV[i]) }             \
    const float er = __expf(ran);                                           \
    _Pragma("unroll")                                                       \
    for (int i = 0; i < 8; ++i) { DOT4(zan, Uz, 4 * i, HV[i]) }             \
    const float ez = __expf(zan);                                           \
    float ca = b1c2;                                                        \
    _Pragma("unroll")                                                       \
    for (int i = 0; i < 8; ++i) { DOT4(ca, Uc, 4 * i, HV[i]) }              \
    const float r  = frcp(1.f + er);                                        \
    const float z  = frcp(1.f + ez);                                        \
    const float y  = fmaf(r, ca, xca);                                      \
    const float cg = 1.f - 2.f * frcp(1.f + __expf(y));                     \
    const float hn = fmaf(z, hold - cg, cg);                                \
    hold = hn;                                                              \
    h16[j] = (_Float16)hn;                                                  \
    { const h8* hp_ = (const h8*)h16;                                       \
      _Pragma("unroll")                                                     \
      for (int i = 0; i < 8; ++i) NHV[i] = hp_[i];                          \
      const h8* xp_ = (const h8*)(xbuf + (((C) + 1) & 63) * 24);            \
      NX0 = xp_[0]; NX1 = xp_[1]; NX2 = xp_[2]; }                           \
    p_lds[(C) * 66 + j] = hn * wdj;                                         \
  }

// stage 24 f32 (global row) -> 24 f16 (xbuf row j), no persistent regs
#define STAGE_ROW(BASEROW)                                                  \
  { const v4f* s_ = (const v4f*)(xsrc + (size_t)(BASEROW) * 24 + j * 24);   \
    const v4f g0_=s_[0],g1_=s_[1],g2_=s_[2],g3_=s_[3],g4_=s_[4],g5_=s_[5];  \
    h8 o0_, o1_, o2_;                                                       \
    _Pragma("unroll")                                                       \
    for (int i_ = 0; i_ < 4; ++i_) {                                        \
        o0_[i_]   = (_Float16)g0_[i_];  o0_[4+i_] = (_Float16)g1_[i_];      \
        o1_[i_]   = (_Float16)g2_[i_];  o1_[4+i_] = (_Float16)g3_[i_];      \
        o2_[i_]   = (_Float16)g4_[i_];  o2_[4+i_] = (_Float16)g5_[i_];      \
    }                                                                       \
    h8* d_ = (h8*)(xbuf + j * 24);                                          \
    d_[0] = o0_; d_[1] = o1_; d_[2] = o2_; }

__global__ __launch_bounds__(64, 1) void gru1_kernel(
    const float* __restrict__ xg,      // (512,1024,24)
    const int*   __restrict__ tg,      // (512,)
    const float* __restrict__ Wg,      // (24,192)
    const float* __restrict__ Ug,      // (64,192)
    const float* __restrict__ bg,      // (2,192)
    const float* __restrict__ Wdg,     // (64,1)
    const float* __restrict__ bdg,     // (1,)
    float*       __restrict__ outg)    // (512,1024)
{
    const int b = blockIdx.x;
    const int j = threadIdx.x;          // lane 0..63

    __shared__ __align__(16) _Float16 h16[64];          // f16 state, 128 B
    __shared__ __align__(16) _Float16 xbuf[64 * 24];    // chunk of x, f16
    __shared__ __align__(16) float    p_lds[64 * 66];   // [step][lane], pad 66
    __shared__ float o_last;

    const int   t    = tg[b];
    float*      outb = outg + (size_t)b * 1024;
    const float bdv  = bdg[0];

    if (t <= 0) {
        const float fill = frcp(1.f + __expf(-bdv));
        for (int i = j; i < 1024; i += 64) outb[i] = fill;
        return;
    }

    // ---- weight preload: f16 pairs along K; z/r negated, c doubled ----
    h2 Uz[32], Ur[32], Uc[32];
    #pragma unroll
    for (int k = 0; k < 32; ++k) {
        const float* r0 = Ug + (2 * k)     * 192;
        const float* r1 = Ug + (2 * k + 1) * 192;
        Uz[k] = (h2){ (_Float16)(-r0[j]),            (_Float16)(-r1[j]) };
        Ur[k] = (h2){ (_Float16)(-r0[64 + j]),       (_Float16)(-r1[64 + j]) };
        Uc[k] = (h2){ (_Float16)(2.f * r0[128 + j]), (_Float16)(2.f * r1[128 + j]) };
    }
    h2 Wz[12], Wr[12], Wc[12];
    #pragma unroll
    for (int d = 0; d < 12; ++d) {
        const float* r0 = Wg + (2 * d)     * 192;
        const float* r1 = Wg + (2 * d + 1) * 192;
        Wz[d] = (h2){ (_Float16)(-r0[j]),            (_Float16)(-r1[j]) };
        Wr[d] = (h2){ (_Float16)(-r0[64 + j]),       (_Float16)(-r1[64 + j]) };
        Wc[d] = (h2){ (_Float16)(2.f * r0[128 + j]), (_Float16)(2.f * r1[128 + j]) };
    }
    const float bzn  = -(bg[j]      + bg[192 + j]);     // z: negated
    const float brn  = -(bg[64 + j] + bg[256 + j]);     // r: negated
    const float b0c2 = 2.f * bg[128 + j];               // c: doubled
    const float b1c2 = 2.f * bg[320 + j];
    const float wdj  = Wdg[j];

    const float* xsrc = xg + (size_t)b * 24576;   // 1024*24

    // ---- stage chunk 0; zero h; fill ping-pong set A ----
    STAGE_ROW(0);
    h16[j] = (_Float16)0.f;

    h8 hvA[8], hvB[8];
    h8 xaA, xbA, xcA, xaB, xbB, xcB;
    {
        const h8* hp = (const h8*)h16;
        #pragma unroll
        for (int i = 0; i < 8; ++i) hvA[i] = hp[i];
        const h8* xp = (const h8*)xbuf;
        xaA = xp[0]; xbA = xp[1]; xcA = xp[2];
    }

    float hold = 0.f;   // lane j's own h_j (f32, full precision)

    for (int base = 0; base < t; base += 64) {
        const int cnt = (t - base < 64) ? (t - base) : 64;

        if (base > 0) {
            // previous chunk done (64 steps, even -> active set is A).
            // Reduce previous outputs, commit this chunk's x (direct global
            // read, no persistent prefetch regs), re-read x row 0 into A.
            {
                const v2f* pr = (const v2f*)(p_lds + j * 66);
                v2f s2 = (v2f){0.f, 0.f};
                #pragma unroll
                for (int i = 0; i < 32; ++i) s2 += pr[i];
                outb[base - 64 + j] = frcp(1.f + __expf(-(s2.x + s2.y + bdv)));
            }
            STAGE_ROW(base);
            {
                const h8* xp = (const h8*)xbuf;
                xaA = xp[0]; xbA = xp[1]; xcA = xp[2];
            }
            // hvA carries over: last step's reads saw the current h16.
        }

        // ---- 2x-unrolled ping-pong steps (overrun by one harmless on the
        //      final odd chunk: p rows >= cnt are never reduced, h unused) ----
        for (int c = 0; c < cnt; c += 2) {
            GRU_STEP(c,     hvA, xaA, xbA, xcA, hvB, xaB, xbB, xcB)
            GRU_STEP(c + 1, hvB, xaB, xbB, xcB, hvA, xaA, xbA, xcA)
        }
    }

    // ---- final (possibly partial) chunk reduce ----
    const int lastbase = ((t - 1) >> 6) << 6;
    const int lastcnt  = t - lastbase;
    if (j < lastcnt) {
        const v2f* pr = (const v2f*)(p_lds + j * 66);
        v2f s2 = (v2f){0.f, 0.f};
        #pragma unroll
        for (int i = 0; i < 32; ++i) s2 += pr[i];
        const float o = frcp(1.f + __expf(-(s2.x + s2.y + bdv)));
        outb[lastbase + j] = o;
        if (j == lastcnt - 1) o_last = o;
    }
    // ---- constant tail fill (same-wave visibility; R3-proven pattern) ----
    const float fill = o_last;
    for (int i = t + j; i < 1024; i += 64) outb[i] = fill;
}

extern "C" void kernel_launch(void* const* d_in, const int* in_sizes, int n_in,
                              void* d_out, int out_size, void* d_ws, size_t ws_size,
                              hipStream_t stream) {
    (void)in_sizes; (void)n_in; (void)d_ws; (void)ws_size; (void)out_size;
    const float* x  = (const float*)d_in[0];
    const int*   t  = (const int*)d_in[1];
    const float* W  = (const float*)d_in[2];
    const float* U  = (const float*)d_in[3];
    const float* bb = (const float*)d_in[4];
    const float* Wd = (const float*)d_in[5];
    const float* bd = (const float*)d_in[6];
    float* out = (float*)d_out;

    hipLaunchKernelGGL(gru1_kernel, dim3(512), dim3(64), 0, stream,
                       x, t, W, U, bb, Wd, bd, out);
}